// Round 4
// baseline (12.902 us; speedup 1.0000x reference)
//
#include <hip/hip_runtime.h>
#include <stdint.h>

typedef unsigned long long u64;
typedef float f32x4 __attribute__((ext_vector_type(4)));

// SC polar decode, N=256, frozen = [0,128). Collapses to:
//   x_j = (in[b,j] + in[b,j+128] >= 0),  j in [0,128)
//   out[b,:] = T(x),  T = F^{(x)7} over GF(2) (self-inverse polar transform).
// T is equivariant under any permutation of the 7 index BITS, so the
// word-butterfly runs directly in the packed bit-domain the ballots produce.
//
// NOTE: no nontemporal hints — input (31 MB) is read-only across graph
// replays and fully L3-resident (256 MiB); nt was forcing HBM re-fetch.

__device__ __forceinline__ void butterfly128(u64& w0, u64& w1) {
    w0 ^= w1;                                    // top index bit (word select)
    w0 ^= w0 >> 32;                              w1 ^= w1 >> 32;
    w0 ^= (w0 >> 16) & 0x0000FFFF0000FFFFull;    w1 ^= (w1 >> 16) & 0x0000FFFF0000FFFFull;
    w0 ^= (w0 >> 8)  & 0x00FF00FF00FF00FFull;    w1 ^= (w1 >> 8)  & 0x00FF00FF00FF00FFull;
    w0 ^= (w0 >> 4)  & 0x0F0F0F0F0F0F0F0Full;    w1 ^= (w1 >> 4)  & 0x0F0F0F0F0F0F0F0Full;
    w0 ^= (w0 >> 2)  & 0x3333333333333333ull;    w1 ^= (w1 >> 2)  & 0x3333333333333333ull;
    w0 ^= (w0 >> 1)  & 0x5555555555555555ull;    w1 ^= (w1 >> 1)  & 0x5555555555555555ull;
}

__global__ __launch_bounds__(256) void sc_dec_kernel(const float* __restrict__ in,
                                                     float* __restrict__ out,
                                                     int rows) {
    const int lane = threadIdx.x & 63;
    const int h = lane >> 5;          // which row of the pair this lane serves
    const int m = lane & 31;
    const int wave = blockIdx.x * (blockDim.x >> 6) + (threadIdx.x >> 6);
    const int r = wave * 8;           // 8 rows per wave (4 pairs)
    if (r >= rows) return;

    if (r + 8 <= rows) {
        const f32x4* ib = reinterpret_cast<const f32x4*>(in) + (size_t)r * 64;
        const int oA = (h << 6) + m;  // row (pr+h) first half  (f32x4 units)
        const int oB = oA + 32;       // row (pr+h) second half

        // hoist all 8 loads: 128 B/lane, 8 KiB/wave in flight
        f32x4 A[4], B[4];
#pragma unroll
        for (int p = 0; p < 4; ++p) {
            const f32x4* pb = ib + (size_t)p * 128;   // rows r+2p, r+2p+1
            A[p] = pb[oA];
            B[p] = pb[oB];
        }

        f32x4* ob = reinterpret_cast<f32x4*>(out) + (size_t)r * 32;
#pragma unroll
        for (int p = 0; p < 4; ++p) {
            // lanes 0-31: row r+2p; lanes 32-63: row r+2p+1
            u64 M0 = __ballot(A[p].x + B[p].x >= 0.0f);
            u64 M1 = __ballot(A[p].y + B[p].y >= 0.0f);
            u64 M2 = __ballot(A[p].z + B[p].z >= 0.0f);
            u64 M3 = __ballot(A[p].w + B[p].w >= 0.0f);
            u64 a0 = (M0 & 0xFFFFFFFFull) | (M1 << 32);          // row r+2p
            u64 a1 = (M2 & 0xFFFFFFFFull) | (M3 << 32);
            u64 c0 = (M0 >> 32) | (M1 & 0xFFFFFFFF00000000ull);  // row r+2p+1
            u64 c1 = (M2 >> 32) | (M3 & 0xFFFFFFFF00000000ull);
            butterfly128(a0, a1);
            butterfly128(c0, c1);
            u64 w0 = h ? c0 : a0, w1 = h ? c1 : a1;
            f32x4 o;
            o.x = (float)((w0 >> m) & 1ull);
            o.y = (float)((w0 >> (m + 32)) & 1ull);
            o.z = (float)((w1 >> m) & 1ull);
            o.w = (float)((w1 >> (m + 32)) & 1ull);
            ob[(size_t)p * 64 + (h << 5) + m] = o;
        }
    } else {
        // tail fallback (rows % 8 != 0): per-row float2 scheme
        for (int row = r; row < rows; ++row) {
            const float2* rin = reinterpret_cast<const float2*>(in + (size_t)row * 256);
            float2 a = rin[lane];
            float2 c = rin[64 + lane];
            u64 w0 = __ballot(a.x + c.x >= 0.0f);
            u64 w1 = __ballot(a.y + c.y >= 0.0f);
            butterfly128(w0, w1);
            float2 o;
            o.x = (float)((w0 >> lane) & 1ull);
            o.y = (float)((w1 >> lane) & 1ull);
            reinterpret_cast<float2*>(out + (size_t)row * 128)[lane] = o;
        }
    }
}

extern "C" void kernel_launch(void* const* d_in, const int* in_sizes, int n_in,
                              void* d_out, int out_size, void* d_ws, size_t ws_size,
                              hipStream_t stream) {
    const float* in = (const float*)d_in[0];
    float* out = (float*)d_out;
    const int rows = in_sizes[0] / 256;            // 32768

    const int waves = (rows + 7) / 8;              // 8 rows per wave
    const int blocks = (waves + 3) / 4;            // 4 waves per 256-thread block
    sc_dec_kernel<<<blocks, 256, 0, stream>>>(in, out, rows);
}